// Round 5
// baseline (245.966 us; speedup 1.0000x reference)
//
#include <hip/hip_runtime.h>
#include <math.h>

#define MEM  2048
#define NF4  (MEM / 4)   // 512 float4 per row
#define NT   256
#define NT1  192

typedef float vf4 __attribute__((ext_vector_type(4)));

// Force-issue a 16B global load into a named 128-bit register.
// asm volatile + "memory" pins program order; the register allocator must
// keep every destination live until the explicit waitcnt -> deep MLP.
#define GLOAD(dst, ptr, OFF) \
    asm volatile("global_load_dwordx4 %0, %1, off offset:" #OFF \
                 : "=v"(dst) : "v"(ptr) : "memory")

struct Params {
    const float *lc, *rc, *lh, *rh, *S, *w;
    const float *Wh_w, *Wh_b, *Us_w, *Us_b, *ma_w, *ma_b;
    const float *ilh_w, *ilh_b, *irh_w, *irh_b;
    const float *lflh_w, *lflh_b, *lfrh_w, *lfrh_b;
    const float *rflh_w, *rflh_b, *rfrh_w, *rfrh_b;
    const float *ulh_w, *ulh_b, *urh_w, *urh_b;
    float *pl, *pr, *wml, *wmr, *out;
};

__device__ __forceinline__ float dotv(vf4 a, float4 b) {
    return a[0] * b.x + a[1] * b.y + a[2] * b.z + a[3] * b.w;
}

__device__ __forceinline__ float wave_reduce(float v) {
#pragma unroll
    for (int off = 32; off > 0; off >>= 1)
        v += __shfl_down(v, off, 64);
    return v;
}

// fast tanh/sigmoid via v_exp; |err| ~1e-6 vs libm, tolerance is 3.9e-3.
__device__ __forceinline__ float tanh_fast(float x) {
    x = fminf(15.0f, fmaxf(-15.0f, x));
    const float e = __expf(2.0f * x);
    return (e - 1.0f) / (e + 1.0f);
}
__device__ __forceinline__ float sigmoid_fast(float x) {
    return 1.0f / (1.0f + __expf(-x));
}

// ---- k1: one block per row (grid=2048), 3 waves, one matrix stream per wave.
// asm-burst 8 weight float4 per lane FIRST (all in flight), stage lh/rh/S to
// LDS under the burst, one waitcnt, then consume from LDS.
__global__ __launch_bounds__(NT1, 4) void k1(Params p)
{
    __shared__ __align__(16) float s_l[MEM];
    __shared__ __align__(16) float s_r[MEM];
    __shared__ __align__(16) float s_s[MEM];
    __shared__ float s_par[5];

    const int t   = threadIdx.x;
    const int wv  = t >> 6, ln = t & 63;
    const int row = blockIdx.x;

    // wave-owned matrix stream
    const float* mat = (wv == 0) ? p.Wh_w : (wv == 1) ? p.Us_w : p.ma_w;
    const float* pa  = mat + (size_t)row * MEM + 4 * ln;   // lane base
    const float* pa2 = pa + 1024;                          // +4096 B

    vf4 m0, m1, m2, m3, m4, m5, m6, m7;
    GLOAD(m0, pa,  0);    GLOAD(m1, pa,  1024);
    GLOAD(m2, pa,  2048); GLOAD(m3, pa,  3072);
    GLOAD(m4, pa2, 0);    GLOAD(m5, pa2, 1024);
    GLOAD(m6, pa2, 2048); GLOAD(m7, pa2, 3072);

    // stage x vectors to LDS while the weight burst is in flight
    {
        const float4* l4g = (const float4*)p.lh;
        const float4* r4g = (const float4*)p.rh;
        const float4* s4g = (const float4*)p.S;
        float4* sl = (float4*)s_l;
        float4* sr = (float4*)s_r;
        float4* ss = (float4*)s_s;
        for (int i = t; i < NF4; i += NT1) {
            sl[i] = l4g[i];
            sr[i] = r4g[i];
            ss[i] = s4g[i];
        }
    }
    asm volatile("s_waitcnt vmcnt(0)" ::: "memory");
    __builtin_amdgcn_sched_barrier(0);
    __syncthreads();

    const float4* sl4 = (const float4*)s_l;
    const float4* sr4 = (const float4*)s_r;
    const float4* ss4 = (const float4*)s_s;

    if (wv == 0) {
        float awl = 0.f, awr = 0.f;
        awl += dotv(m0, sl4[ln +   0]); awr += dotv(m0, sr4[ln +   0]);
        awl += dotv(m1, sl4[ln +  64]); awr += dotv(m1, sr4[ln +  64]);
        awl += dotv(m2, sl4[ln + 128]); awr += dotv(m2, sr4[ln + 128]);
        awl += dotv(m3, sl4[ln + 192]); awr += dotv(m3, sr4[ln + 192]);
        awl += dotv(m4, sl4[ln + 256]); awr += dotv(m4, sr4[ln + 256]);
        awl += dotv(m5, sl4[ln + 320]); awr += dotv(m5, sr4[ln + 320]);
        awl += dotv(m6, sl4[ln + 384]); awr += dotv(m6, sr4[ln + 384]);
        awl += dotv(m7, sl4[ln + 448]); awr += dotv(m7, sr4[ln + 448]);
        awl = wave_reduce(awl);
        awr = wave_reduce(awr);
        if (ln == 0) { s_par[0] = awl; s_par[1] = awr; }
    } else if (wv == 1) {
        float aus = 0.f;
        aus += dotv(m0, ss4[ln +   0]);
        aus += dotv(m1, ss4[ln +  64]);
        aus += dotv(m2, ss4[ln + 128]);
        aus += dotv(m3, ss4[ln + 192]);
        aus += dotv(m4, ss4[ln + 256]);
        aus += dotv(m5, ss4[ln + 320]);
        aus += dotv(m6, ss4[ln + 384]);
        aus += dotv(m7, ss4[ln + 448]);
        aus = wave_reduce(aus);
        if (ln == 0) s_par[2] = aus;
    } else {
        float aml = 0.f, amr = 0.f;
        aml += dotv(m0, sl4[ln +   0]); amr += dotv(m0, sr4[ln +   0]);
        aml += dotv(m1, sl4[ln +  64]); amr += dotv(m1, sr4[ln +  64]);
        aml += dotv(m2, sl4[ln + 128]); amr += dotv(m2, sr4[ln + 128]);
        aml += dotv(m3, sl4[ln + 192]); amr += dotv(m3, sr4[ln + 192]);
        aml += dotv(m4, sl4[ln + 256]); amr += dotv(m4, sr4[ln + 256]);
        aml += dotv(m5, sl4[ln + 320]); amr += dotv(m5, sr4[ln + 320]);
        aml += dotv(m6, sl4[ln + 384]); amr += dotv(m6, sr4[ln + 384]);
        aml += dotv(m7, sl4[ln + 448]); amr += dotv(m7, sr4[ln + 448]);
        aml = wave_reduce(aml);
        amr = wave_reduce(amr);
        if (ln == 0) { s_par[3] = aml; s_par[4] = amr; }
    }
    __syncthreads();

    if (t == 0) {
        const float us  = s_par[2] + p.Us_b[row];
        const float whb = p.Wh_b[row];
        const float ml  = tanh_fast(s_par[0] + whb + us);
        const float mr  = tanh_fast(s_par[1] + whb + us);
        p.pl[row] = s_par[3];
        p.pr[row] = s_par[4];
        const float wj = p.w[row];
        p.wml[row] = wj * ml;
        p.wmr[row] = wj * mr;
    }
}

// ---- kmid: ONE block. Global reduce of wml/wmr -> alpha; writes
// xa = tanh(al*pl + ma_b), xb = tanh(ar*pr + ma_b) in place over wml/wmr.
__global__ __launch_bounds__(NT) void kmid(Params p)
{
    __shared__ float s_red[4][2];
    __shared__ float s_al[2];

    const int t  = threadIdx.x;
    const int wv = t >> 6, ln = t & 63;

    const float4* wl4 = (const float4*)p.wml;
    const float4* wr4 = (const float4*)p.wmr;
    const float4 a0 = wl4[t], a1 = wl4[t + NT];
    const float4 b0 = wr4[t], b1 = wr4[t + NT];
    float el = a0.x + a0.y + a0.z + a0.w + a1.x + a1.y + a1.z + a1.w;
    float er = b0.x + b0.y + b0.z + b0.w + b1.x + b1.y + b1.z + b1.w;
    el = wave_reduce(el);
    er = wave_reduce(er);
    if (ln == 0) { s_red[wv][0] = el; s_red[wv][1] = er; }
    __syncthreads();
    if (t == 0) {
        const float e0 = s_red[0][0] + s_red[1][0] + s_red[2][0] + s_red[3][0];
        const float e1 = s_red[0][1] + s_red[1][1] + s_red[2][1] + s_red[3][1];
        const float d  = e0 + e1;
        s_al[0] = e0 / d;
        s_al[1] = e1 / d;
    }
    __syncthreads();
    const float al = s_al[0];
    const float ar = s_al[1];

    const float4* p4 = (const float4*)p.pl;
    const float4* q4 = (const float4*)p.pr;
    const float4* b4 = (const float4*)p.ma_b;
    float4* xa4 = (float4*)p.wml;
    float4* xb4 = (float4*)p.wmr;
#pragma unroll
    for (int h = 0; h < 2; ++h) {
        const int i = t + h * NT;
        const float4 pp = p4[i];
        const float4 qq = q4[i];
        const float4 bb = b4[i];
        float4 xa, xb;
        xa.x = tanh_fast(al * pp.x + bb.x); xb.x = tanh_fast(ar * qq.x + bb.x);
        xa.y = tanh_fast(al * pp.y + bb.y); xb.y = tanh_fast(ar * qq.y + bb.y);
        xa.z = tanh_fast(al * pp.z + bb.z); xb.z = tanh_fast(ar * qq.z + bb.z);
        xa.w = tanh_fast(al * pp.w + bb.w); xb.w = tanh_fast(ar * qq.w + bb.w);
        xa4[i] = xa;
        xb4[i] = xb;
    }
}

// ---- k2: one block per row (grid=2048). Wave wv owns one gate pair.
// asm-burst 16 weight float4 per lane (forced into 64 VGPRs, all in flight),
// stage xa/xb to LDS under the burst, one waitcnt, consume from LDS.
__global__ __launch_bounds__(NT, 4) void k2(Params p)
{
    __shared__ __align__(16) float s_xa[MEM];
    __shared__ __align__(16) float s_xb[MEM];
    __shared__ float s_g[4];

    const int t   = threadIdx.x;
    const int wv  = t >> 6, ln = t & 63;
    const int row = blockIdx.x;

    // per-row scalars (wave-uniform -> s_load), issued first
    const float bI  = p.ilh_b[row]  + p.irh_b[row];
    const float bLF = p.lflh_b[row] + p.lfrh_b[row];
    const float bRF = p.rflh_b[row] + p.rfrh_b[row];
    const float bU  = p.ulh_b[row]  + p.urh_b[row];
    const float lcv = p.lc[row], rcv = p.rc[row];

    const float *wlp, *wrp;
    if      (wv == 0) { wlp = p.ilh_w;  wrp = p.irh_w;  }
    else if (wv == 1) { wlp = p.lflh_w; wrp = p.lfrh_w; }
    else if (wv == 2) { wlp = p.rflh_w; wrp = p.rfrh_w; }
    else              { wlp = p.ulh_w;  wrp = p.urh_w;  }

    const float* pa  = wlp + (size_t)row * MEM + 4 * ln;
    const float* pb  = wrp + (size_t)row * MEM + 4 * ln;
    const float* pa2 = pa + 1024;
    const float* pb2 = pb + 1024;

    vf4 a0, a1, a2, a3, a4, a5, a6, a7;
    vf4 b0, b1, b2, b3, b4, b5, b6, b7;
    GLOAD(a0, pa,  0);    GLOAD(a1, pa,  1024);
    GLOAD(a2, pa,  2048); GLOAD(a3, pa,  3072);
    GLOAD(a4, pa2, 0);    GLOAD(a5, pa2, 1024);
    GLOAD(a6, pa2, 2048); GLOAD(a7, pa2, 3072);
    GLOAD(b0, pb,  0);    GLOAD(b1, pb,  1024);
    GLOAD(b2, pb,  2048); GLOAD(b3, pb,  3072);
    GLOAD(b4, pb2, 0);    GLOAD(b5, pb2, 1024);
    GLOAD(b6, pb2, 2048); GLOAD(b7, pb2, 3072);

    // stage xa/xb (written by kmid over wml/wmr) to LDS under the burst
    {
        const float4* xag4 = (const float4*)p.wml;
        const float4* xbg4 = (const float4*)p.wmr;
        float4* sa = (float4*)s_xa;
        float4* sb = (float4*)s_xb;
        sa[t]      = xag4[t];
        sa[t + NT] = xag4[t + NT];
        sb[t]      = xbg4[t];
        sb[t + NT] = xbg4[t + NT];
    }
    asm volatile("s_waitcnt vmcnt(0)" ::: "memory");
    __builtin_amdgcn_sched_barrier(0);
    __syncthreads();

    const float4* xa4 = (const float4*)s_xa;
    const float4* xb4 = (const float4*)s_xb;

    float accA = 0.f, accB = 0.f;
    accA += dotv(a0, xa4[ln +   0]);  accB += dotv(b0, xb4[ln +   0]);
    accA += dotv(a1, xa4[ln +  64]);  accB += dotv(b1, xb4[ln +  64]);
    accA += dotv(a2, xa4[ln + 128]);  accB += dotv(b2, xb4[ln + 128]);
    accA += dotv(a3, xa4[ln + 192]);  accB += dotv(b3, xb4[ln + 192]);
    accA += dotv(a4, xa4[ln + 256]);  accB += dotv(b4, xb4[ln + 256]);
    accA += dotv(a5, xa4[ln + 320]);  accB += dotv(b5, xb4[ln + 320]);
    accA += dotv(a6, xa4[ln + 384]);  accB += dotv(b6, xb4[ln + 384]);
    accA += dotv(a7, xa4[ln + 448]);  accB += dotv(b7, xb4[ln + 448]);

    const float g = wave_reduce(accA + accB);
    if (ln == 0) s_g[wv] = g;
    __syncthreads();

    if (t == 0) {
        const float ig  = sigmoid_fast(s_g[0] + bI);
        const float lfg = sigmoid_fast(s_g[1] + bLF);
        const float rfg = sigmoid_fast(s_g[2] + bRF);
        const float ug  = tanh_fast(s_g[3] + bU);
        const float c   = ig * ug + lfg * lcv + rfg * rcv;
        p.out[row]       = c;
        p.out[MEM + row] = tanh_fast(c);
    }
}

extern "C" void kernel_launch(void* const* d_in, const int* in_sizes, int n_in,
                              void* d_out, int out_size, void* d_ws, size_t ws_size,
                              hipStream_t stream)
{
    Params h;
    h.lc = (const float*)d_in[0];
    h.lh = (const float*)d_in[1];
    h.rc = (const float*)d_in[2];
    h.rh = (const float*)d_in[3];
    h.S  = (const float*)d_in[4];
    h.w  = (const float*)d_in[5];
    h.Wh_w   = (const float*)d_in[6];   h.Wh_b   = (const float*)d_in[7];
    h.Us_w   = (const float*)d_in[8];   h.Us_b   = (const float*)d_in[9];
    h.ma_w   = (const float*)d_in[10];  h.ma_b   = (const float*)d_in[11];
    h.ilh_w  = (const float*)d_in[12];  h.ilh_b  = (const float*)d_in[13];
    h.irh_w  = (const float*)d_in[14];  h.irh_b  = (const float*)d_in[15];
    h.lflh_w = (const float*)d_in[16];  h.lflh_b = (const float*)d_in[17];
    h.lfrh_w = (const float*)d_in[18];  h.lfrh_b = (const float*)d_in[19];
    h.rflh_w = (const float*)d_in[20];  h.rflh_b = (const float*)d_in[21];
    h.rfrh_w = (const float*)d_in[22];  h.rfrh_b = (const float*)d_in[23];
    h.ulh_w  = (const float*)d_in[24];  h.ulh_b  = (const float*)d_in[25];
    h.urh_w  = (const float*)d_in[26];  h.urh_b  = (const float*)d_in[27];

    float* ws = (float*)d_ws;
    h.pl  = ws;
    h.pr  = ws + MEM;
    h.wml = ws + 2 * MEM;   // becomes xa after kmid
    h.wmr = ws + 3 * MEM;   // becomes xb after kmid
    h.out = (float*)d_out;

    k1  <<<MEM, NT1, 0, stream>>>(h);
    kmid<<<1,   NT,  0, stream>>>(h);
    k2  <<<MEM, NT,  0, stream>>>(h);
}